// Round 20
// baseline (594.402 us; speedup 1.0000x reference)
//
#include <hip/hip_runtime.h>
#include <cstddef>

#define NPTS   40000
#define NGRP   256
#define GSZ    64
#define FDIM   768
#define BATCH  2

#define FPS_BPB    32
#define FPS_NBLK   (FPS_BPB * BATCH)   // 64
#define FPS_TPB    64
#define FPS_PPB    (NPTS / FPS_BPB)    // 1250
#define FPS_PPT    20
#define MB_ROUNDS  255
#define NCHUNK     (NPTS / 64)         // 625

#define W_NBLK     (BATCH * NGRP)      // 512 worker blocks
#define GRID_BLK   (FPS_NBLK + W_NBLK) // 576
#define DC_REP     8                   // done-counter replicas (64B-spaced)

__device__ __forceinline__ unsigned long long mk32(float v, unsigned tb) {
    return ((unsigned long long)__float_as_uint(v) << 16) | (unsigned long long)tb;
}
__device__ __forceinline__ float d2f(float px, float py, float pz,
                                     float cx, float cy, float cz) {
    float dx = __fsub_rn(px, cx), dy = __fsub_rn(py, cy), dz = __fsub_rn(pz, cz);
    return __fmaf_rn(dz, dz, __fmaf_rn(dy, dy, __fmul_rn(dx, dx)));
}
__device__ __forceinline__ unsigned long long knn_key(double v, int idx) {
    unsigned long long bits = (unsigned long long)__double_as_longlong(v);
    return (bits & 0xFFFFFFFFFFFF0000ull) | (unsigned long long)(unsigned)idx;
}
__device__ __forceinline__ unsigned long long fps_mk64(double v, unsigned tb) {
    return (((unsigned long long)__double_as_longlong(v)) & 0xFFFFFFFFFFFF0000ull)
         | (unsigned long long)tb;
}
__device__ __forceinline__ unsigned long long wave_max_u64(unsigned long long k) {
#pragma unroll
    for (int off = 32; off >= 1; off >>= 1) {
        unsigned long long o = __shfl_xor(k, off, 64);
        k = o > k ? o : k;
    }
    return k;
}

#define LANE_RESCAN(OUT)                                                    \
    {                                                                       \
        unsigned long long bb_ = 0ull;                                      \
        _Pragma("unroll")                                                   \
        for (int j_ = 0; j_ < FPS_PPT; ++j_) {                              \
            bool live_ = (((vmask >> j_) & 1u) != 0u) &&                    \
                         (((cons >> j_) & 1u) == 0u);                       \
            unsigned long long kk_ = live_                                  \
                ? mk32(dist[j_], tb0 - (unsigned)(j_ << 6)) : 0ull;         \
            bb_ = kk_ > bb_ ? kk_ : bb_;                                    \
        }                                                                   \
        OUT = bb_;                                                          \
    }

// ============ fused: FPS (blocks 0..63, 1 wave) + workers (one per center) ============
template<int M>
__global__ void __launch_bounds__(256) fused_kernel(
    const float* __restrict__ xyz,
    const float* __restrict__ fts,
    const int*   __restrict__ valid,
    float* __restrict__ all_fts,
    float* __restrict__ mask,
    float* __restrict__ centers,
    unsigned long long* __restrict__ mb,      // [MB_ROUNDS][64*M], pre-zeroed
    unsigned int* __restrict__ dcnt)          // [DC_REP][16] replicas, pre-zeroed
{
    constexpr int Q     = (FPS_BPB * M) / 64;
    constexpr int MB_RW = FPS_NBLK * M;

    const int bid = blockIdx.x;
    const int tid = threadIdx.x;

    if (bid < FPS_NBLK) {
        // ================= FPS role: R13/R16-proven fps_spec<16> f32 =========
        if (tid >= 64) return;               // waves 1..3 exit
        const int lane = tid;
        const int b    = bid >> 5;
        const int lb   = bid & 31;
        const float* __restrict__ X = xyz + (size_t)b * NPTS * 3;
        const int base = lb * FPS_PPB;
        const unsigned tb0 = 0xFFFFu - (unsigned)(base + lane);

        float px[FPS_PPT], py[FPS_PPT], pz[FPS_PPT], dist[FPS_PPT];
        unsigned vmask = 0;
#pragma unroll
        for (int j = 0; j < FPS_PPT; ++j) {
            int loc = lane + j * FPS_TPB;
            bool ok = loc < FPS_PPB;
            int i   = base + (ok ? loc : 0);
            px[j] = X[i * 3 + 0]; py[j] = X[i * 3 + 1]; pz[j] = X[i * 3 + 2];
            if (ok) vmask |= 1u << j;
        }
        {
            float cx = X[0], cy = X[1], cz = X[2];
            if (lb == 0 && lane == 0) {
                centers[(size_t)(b * NGRP) * 3 + 0] = cx;
                centers[(size_t)(b * NGRP) * 3 + 1] = cy;
                centers[(size_t)(b * NGRP) * 3 + 2] = cz;
            }
            if (lb == 0) {
                // wave-wide release: s_waitcnt drains lane0's center writes
                __builtin_amdgcn_fence(__ATOMIC_RELEASE, "agent");
                if (lane < DC_REP)
                    __hip_atomic_store(&dcnt[lane * 16 + b], 1u,
                                       __ATOMIC_RELAXED, __HIP_MEMORY_SCOPE_AGENT);
            }
#pragma unroll
            for (int j = 0; j < FPS_PPT; ++j)
                dist[j] = d2f(px[j], py[j], pz[j], cx, cy, cz);
        }

        int done = 1;
        int r = 0;

        while (done < NGRP) {
            unsigned long long s0 = 0, s1 = 0, s2 = 0, s3 = 0;
#pragma unroll
            for (int j = 0; j < FPS_PPT; ++j) {
                bool live = ((vmask >> j) & 1u) != 0u;
                unsigned long long kk = live ? mk32(dist[j], tb0 - (unsigned)(j << 6)) : 0ull;
                unsigned long long t;
                t = kk > s0 ? kk : s0;  kk = kk > s0 ? s0 : kk;  s0 = t;
                t = kk > s1 ? kk : s1;  kk = kk > s1 ? s1 : kk;  s1 = t;
                t = kk > s2 ? kk : s2;  kk = kk > s2 ? s2 : kk;  s2 = t;
                s3 = kk > s3 ? kk : s3;
            }
            unsigned cons = 0;

            unsigned long long myMsg = 0;
#pragma unroll
            for (int i = 0; i < M; ++i) {
                if (s0 == 0ull) LANE_RESCAN(s0);
                unsigned long long g = wave_max_u64(s0);
                if (s0 == g && g != 0ull) {
                    unsigned idx = 0xFFFFu - (unsigned)(g & 0xFFFFull);
                    unsigned jj  = (idx - (unsigned)(base + lane)) >> 6;
                    cons |= 1u << jj;
                    s0 = s1; s1 = s2; s2 = s3; s3 = 0ull;
                }
                myMsg = (lane == i) ? g : myMsg;
            }

            if (lane < M)
                __hip_atomic_store(&mb[(size_t)r * MB_RW + bid * M + lane], myMsg,
                                   __ATOMIC_RELAXED, __HIP_MEMORY_SCOPE_AGENT);

            const unsigned long long* pb = mb + (size_t)r * MB_RW + b * (FPS_BPB * M);
            unsigned long long w[Q];
#pragma unroll
            for (int q = 0; q < Q; ++q)
                w[q] = __hip_atomic_load(pb + lane + 64 * q,
                                         __ATOMIC_RELAXED, __HIP_MEMORY_SCOPE_AGENT);
            for (;;) {
                bool miss = false;
#pragma unroll
                for (int q = 0; q < Q; ++q) miss |= (w[q] == 0ull);
                if (__ballot(miss) == 0ull) break;
#pragma unroll
                for (int q = 0; q < Q; ++q)
                    if (w[q] == 0ull)
                        w[q] = __hip_atomic_load(pb + lane + 64 * q,
                                                 __ATOMIC_RELAXED, __HIP_MEMORY_SCOPE_AGENT);
            }

            unsigned long long tl = 0;
            if ((lane & (M - 1)) == (M - 1)) {
#pragma unroll
                for (int q = 0; q < Q; ++q) tl = w[q] > tl ? w[q] : tl;
            }
            const unsigned long long T = wave_max_u64(tl);

            float cvv[Q]; unsigned ctb[Q]; unsigned long long ck[Q];
            float ccx[Q], ccy[Q], ccz[Q];
#pragma unroll
            for (int q = 0; q < Q; ++q) {
                ck[q]  = w[q];
                ctb[q] = (unsigned)(w[q] & 0xFFFFull);
                cvv[q] = __uint_as_float((unsigned)(w[q] >> 16));
                int ii = (int)(0xFFFFu - ctb[q]);
                ccx[q] = X[ii * 3 + 0]; ccy[q] = X[ii * 3 + 1]; ccz[q] = X[ii * 3 + 2];
            }
            unsigned consq = 0;

#pragma unroll 1
            for (int s = 0; s < 64; ++s) {
                unsigned long long lk = 0;
#pragma unroll
                for (int q = 0; q < Q; ++q) {
                    unsigned long long kk = ((consq >> q) & 1u) ? 0ull : ck[q];
                    lk = kk > lk ? kk : lk;
                }
                unsigned long long g = wave_max_u64(lk);
                if (s > 0 && g < T) break;

                float sx = ccx[0], sy = ccy[0], sz = ccz[0];
#pragma unroll
                for (int q = 0; q < Q; ++q) {
                    bool hit = (ck[q] == g) && !((consq >> q) & 1u);
                    consq |= hit ? (1u << q) : 0u;
                    sx = hit ? ccx[q] : sx;
                    sy = hit ? ccy[q] : sy;
                    sz = hit ? ccz[q] : sz;
                }
                unsigned long long om = __ballot(lk == g);
                int owner = __ffsll((long long)om) - 1;
                float wx = __shfl(sx, owner, 64);
                float wy = __shfl(sy, owner, 64);
                float wz = __shfl(sz, owner, 64);
                if (lb == 0 && lane == 0) {
                    centers[((size_t)b * NGRP + done) * 3 + 0] = wx;
                    centers[((size_t)b * NGRP + done) * 3 + 1] = wy;
                    centers[((size_t)b * NGRP + done) * 3 + 2] = wz;
                }
#pragma unroll
                for (int q = 0; q < Q; ++q) {
                    cvv[q] = fminf(cvv[q], d2f(ccx[q], ccy[q], ccz[q], wx, wy, wz));
                    ck[q]  = ((consq >> q) & 1u) ? 0ull
                           : (((unsigned long long)__float_as_uint(cvv[q]) << 16)
                              | (unsigned long long)ctb[q]);
                }
#pragma unroll
                for (int j = 0; j < FPS_PPT; ++j)
                    dist[j] = fminf(dist[j], d2f(px[j], py[j], pz[j], wx, wy, wz));
                ++done;
                if (done == NGRP) break;
            }
            // publish progress once per round to all 8 replicas (release-fenced)
            if (lb == 0) {
                __builtin_amdgcn_fence(__ATOMIC_RELEASE, "agent");
                if (lane < DC_REP)
                    __hip_atomic_store(&dcnt[lane * 16 + b], (unsigned)done,
                                       __ATOMIC_RELAXED, __HIP_MEMORY_SCOPE_AGENT);
            }
            ++r;
        }
        return;
    }

    // ================= Worker role: one block per center (R12-proven body) ====
    const int w   = bid - FPS_NBLK;            // [0, 512)
    const int c   = (w >> 1) + ((w & 1) << 8); // interleave batches
    const int b   = c >> 8;
    const int wid  = tid >> 6;
    const int lane = tid & 63;
    const float* __restrict__ X = xyz + (size_t)b * NPTS * 3;

    // wait until this center is published: ONE poller thread, backoff, replica
    {
        const unsigned int want = (unsigned)(c & (NGRP - 1)) + 1u;
        const unsigned int* dp = &dcnt[(bid & (DC_REP - 1)) * 16 + b];
        if (tid == 0) {
            unsigned cur;
            while ((cur = __hip_atomic_load(dp, __ATOMIC_RELAXED,
                                            __HIP_MEMORY_SCOPE_AGENT)) < want) {
                if (want - cur > 16) __builtin_amdgcn_s_sleep(127);
                else                 __builtin_amdgcn_s_sleep(8);
            }
        }
        __syncthreads();
        __builtin_amdgcn_fence(__ATOMIC_ACQUIRE, "agent");  // per-wave L1 invalidate
    }

    const double cx = (double)centers[(size_t)c * 3 + 0];
    const double cy = (double)centers[(size_t)c * 3 + 1];
    const double cz = (double)centers[(size_t)c * 3 + 2];

    unsigned long long slot;
    {
        int i = wid * 64 + lane;
        float x = X[i * 3 + 0], y = X[i * 3 + 1], z = X[i * 3 + 2];
        double dx = (double)x - cx, dy = (double)y - cy, dz = (double)z - cz;
        slot = knn_key(dx * dx + dy * dy + dz * dz, i);
    }
    unsigned long long tau = wave_max_u64(slot);

    float ax, ay, az, bx, by, bz;
    {
        int ia = (wid + 4) * 64 + lane;
        ax = X[ia * 3 + 0]; ay = X[ia * 3 + 1]; az = X[ia * 3 + 2];
        int sb = wid + 8 < NCHUNK ? wid + 8 : NCHUNK - 1;
        int ib = sb * 64 + lane;
        bx = X[ib * 3 + 0]; by = X[ib * 3 + 1]; bz = X[ib * 3 + 2];
    }
    for (int s = wid + 4; s < NCHUNK; s += 4) {
        float x = ax, y = ay, z = az;
        ax = bx; ay = by; az = bz;
        int sp = s + 8 < NCHUNK ? s + 8 : NCHUNK - 1;
        int ip = sp * 64 + lane;
        bx = X[ip * 3 + 0]; by = X[ip * 3 + 1]; bz = X[ip * 3 + 2];

        int i = s * 64 + lane;
        double dx = (double)x - cx, dy = (double)y - cy, dz = (double)z - cz;
        unsigned long long key = knn_key(dx * dx + dy * dy + dz * dz, i);

        unsigned long long cand = __ballot(key < tau);
        while (cand) {
            int l = __ffsll(cand) - 1;
            cand &= cand - 1;
            unsigned long long kc = __shfl(key, l, 64);
            if (kc < tau) {
                unsigned long long om = __ballot(slot == tau);
                int owner = __ffsll(om) - 1;
                if (lane == owner) slot = kc;
                tau = wave_max_u64(slot);
            }
        }
    }

    __shared__ unsigned long long skey[256];
    __shared__ int s_nbr[GSZ];
    skey[tid] = slot;
    __syncthreads();
#pragma unroll
    for (int k = 2; k <= 256; k <<= 1) {
        for (int j = k >> 1; j > 0; j >>= 1) {
            int ixj = tid ^ j;
            if (ixj > tid) {
                unsigned long long a = skey[tid], bb = skey[ixj];
                bool up = ((tid & k) == 0);
                if ((a > bb) == up) { skey[tid] = bb; skey[ixj] = a; }
            }
            __syncthreads();
        }
    }

    if (wid == 0) {
        int idx = (int)(skey[lane] & 0xFFFFull);
        s_nbr[lane] = idx;
        int v = valid[b * NPTS + idx];
        unsigned long long vb = __ballot(v != 0);
        if (lane == 0) mask[c] = vb ? 1.0f : 0.0f;
    }
    __syncthreads();

    const float* __restrict__ F = fts + (size_t)b * NPTS * FDIM;
    float a0 = 0.f, a1 = 0.f, a2 = 0.f, b0 = 0.f, b1 = 0.f, b2 = 0.f;
#pragma unroll 1
    for (int j = 0; j < GSZ; j += 2) {
        const float* r0 = F + (size_t)s_nbr[j]     * FDIM;
        const float* r1 = F + (size_t)s_nbr[j + 1] * FDIM;
        a0 += r0[tid];       b0 += r1[tid];
        a1 += r0[tid + 256]; b1 += r1[tid + 256];
        a2 += r0[tid + 512]; b2 += r1[tid + 512];
    }
    float* o = all_fts + (size_t)c * FDIM;
    o[tid]       = (a0 + b0) * 0.015625f;
    o[tid + 256] = (a1 + b1) * 0.015625f;
    o[tid + 512] = (a2 + b2) * 0.015625f;
}

// ---------------- R4-proven fallback FPS (f64, 1 key/block/iter) ----------------
__global__ void __launch_bounds__(FPS_TPB) fps_kernel(
    const float* __restrict__ xyz,
    float* __restrict__ centers,
    unsigned long long* __restrict__ keys)
{
    const int bid  = blockIdx.x;
    const int b    = bid >> 5;
    const int lb   = bid & 31;
    const int lane = threadIdx.x;
    const float* __restrict__ X = xyz + (size_t)b * NPTS * 3;
    const int base  = lb * FPS_PPB;
    const int gbase = base + lane;

    double px[FPS_PPT], py[FPS_PPT], pz[FPS_PPT], dist[FPS_PPT];
#pragma unroll
    for (int j = 0; j < FPS_PPT; ++j) {
        int loc = lane + j * FPS_TPB;
        bool ok = loc < FPS_PPB;
        int i   = base + (ok ? loc : 0);
        px[j] = (double)X[i * 3 + 0];
        py[j] = (double)X[i * 3 + 1];
        pz[j] = (double)X[i * 3 + 2];
        dist[j] = ok ? 1e18 : -1.0;
    }
    double cx = (double)X[0], cy = (double)X[1], cz = (double)X[2];
    if (lb == 0 && lane == 0) {
        centers[(size_t)(b * NGRP) * 3 + 0] = X[0];
        centers[(size_t)(b * NGRP) * 3 + 1] = X[1];
        centers[(size_t)(b * NGRP) * 3 + 2] = X[2];
    }
    for (int it = 0; it < NGRP - 1; ++it) {
        double bd = -2.0; int bj = 0;
#pragma unroll
        for (int j = 0; j < FPS_PPT; ++j) {
            double dx = px[j] - cx, dy = py[j] - cy, dz = pz[j] - cz;
            double d  = fma(dz, dz, fma(dy, dy, dx * dx));
            double nd = dist[j] < d ? dist[j] : d;
            dist[j] = nd;
            bool better = nd > bd;
            bd = better ? nd : bd;
            bj = better ? j  : bj;
        }
        unsigned long long key = fps_mk64(bd, 0xFFFFu - (unsigned)(gbase + (bj << 6)));
        key = wave_max_u64(key);
        if (lane == 0)
            __hip_atomic_store(&keys[it * FPS_NBLK + bid], key,
                               __ATOMIC_RELAXED, __HIP_MEMORY_SCOPE_AGENT);
        unsigned long long pk = 0;
        if (lane < FPS_BPB) {
            const unsigned long long* sp = &keys[it * FPS_NBLK + b * FPS_BPB + lane];
            do {
                pk = __hip_atomic_load(sp, __ATOMIC_RELAXED, __HIP_MEMORY_SCOPE_AGENT);
            } while (pk == 0ull);
        }
        unsigned long long g = wave_max_u64(pk);
        int widx = 0xFFFF - (int)(g & 0xFFFFull);
        float wx = X[widx * 3 + 0], wy = X[widx * 3 + 1], wz = X[widx * 3 + 2];
        cx = (double)wx; cy = (double)wy; cz = (double)wz;
        if (lb == 0 && lane == 0) {
            centers[(size_t)(b * NGRP + it + 1) * 3 + 0] = wx;
            centers[(size_t)(b * NGRP + it + 1) * 3 + 1] = wy;
            centers[(size_t)(b * NGRP + it + 1) * 3 + 2] = wz;
        }
    }
}

// -------- R12-proven fused KNN (f64) + agg + mask (fallback path) --------
__global__ void __launch_bounds__(256) knn_agg_kernel(
    const float* __restrict__ xyz,
    const float* __restrict__ fts,
    const int*   __restrict__ valid,
    const float* __restrict__ centers,
    float* __restrict__ all_fts,
    float* __restrict__ mask)
{
    const int c    = blockIdx.x;
    const int b    = c >> 8;
    const int tid  = threadIdx.x;
    const int wid  = tid >> 6;
    const int lane = tid & 63;
    const float* __restrict__ X = xyz + (size_t)b * NPTS * 3;

    const double cx = (double)centers[(size_t)c * 3 + 0];
    const double cy = (double)centers[(size_t)c * 3 + 1];
    const double cz = (double)centers[(size_t)c * 3 + 2];

    unsigned long long slot;
    {
        int i = wid * 64 + lane;
        float x = X[i * 3 + 0], y = X[i * 3 + 1], z = X[i * 3 + 2];
        double dx = (double)x - cx, dy = (double)y - cy, dz = (double)z - cz;
        slot = knn_key(dx * dx + dy * dy + dz * dz, i);
    }
    unsigned long long tau = wave_max_u64(slot);

    float ax, ay, az, bx, by, bz;
    {
        int ia = (wid + 4) * 64 + lane;
        ax = X[ia * 3 + 0]; ay = X[ia * 3 + 1]; az = X[ia * 3 + 2];
        int sb = wid + 8 < NCHUNK ? wid + 8 : NCHUNK - 1;
        int ib = sb * 64 + lane;
        bx = X[ib * 3 + 0]; by = X[ib * 3 + 1]; bz = X[ib * 3 + 2];
    }
    for (int s = wid + 4; s < NCHUNK; s += 4) {
        float x = ax, y = ay, z = az;
        ax = bx; ay = by; az = bz;
        int sp = s + 8 < NCHUNK ? s + 8 : NCHUNK - 1;
        int ip = sp * 64 + lane;
        bx = X[ip * 3 + 0]; by = X[ip * 3 + 1]; bz = X[ip * 3 + 2];

        int i = s * 64 + lane;
        double dx = (double)x - cx, dy = (double)y - cy, dz = (double)z - cz;
        unsigned long long key = knn_key(dx * dx + dy * dy + dz * dz, i);

        unsigned long long cand = __ballot(key < tau);
        while (cand) {
            int l = __ffsll(cand) - 1;
            cand &= cand - 1;
            unsigned long long kc = __shfl(key, l, 64);
            if (kc < tau) {
                unsigned long long om = __ballot(slot == tau);
                int owner = __ffsll(om) - 1;
                if (lane == owner) slot = kc;
                tau = wave_max_u64(slot);
            }
        }
    }

    __shared__ unsigned long long skey[256];
    __shared__ int s_nbr[GSZ];
    skey[tid] = slot;
    __syncthreads();
#pragma unroll
    for (int k = 2; k <= 256; k <<= 1) {
        for (int j = k >> 1; j > 0; j >>= 1) {
            int ixj = tid ^ j;
            if (ixj > tid) {
                unsigned long long a = skey[tid], bb = skey[ixj];
                bool up = ((tid & k) == 0);
                if ((a > bb) == up) { skey[tid] = bb; skey[ixj] = a; }
            }
            __syncthreads();
        }
    }

    if (wid == 0) {
        int idx = (int)(skey[lane] & 0xFFFFull);
        s_nbr[lane] = idx;
        int v = valid[b * NPTS + idx];
        unsigned long long vb = __ballot(v != 0);
        if (lane == 0) mask[c] = vb ? 1.0f : 0.0f;
    }
    __syncthreads();

    const float* __restrict__ F = fts + (size_t)b * NPTS * FDIM;
    float a0 = 0.f, a1 = 0.f, a2 = 0.f, b0 = 0.f, b1 = 0.f, b2 = 0.f;
#pragma unroll 1
    for (int j = 0; j < GSZ; j += 2) {
        const float* r0 = F + (size_t)s_nbr[j]     * FDIM;
        const float* r1 = F + (size_t)s_nbr[j + 1] * FDIM;
        a0 += r0[tid];       b0 += r1[tid];
        a1 += r0[tid + 256]; b1 += r1[tid + 256];
        a2 += r0[tid + 512]; b2 += r1[tid + 512];
    }
    float* o = all_fts + (size_t)c * FDIM;
    o[tid]       = (a0 + b0) * 0.015625f;
    o[tid + 256] = (a1 + b1) * 0.015625f;
    o[tid + 512] = (a2 + b2) * 0.015625f;
}

extern "C" void kernel_launch(void* const* d_in, const int* in_sizes, int n_in,
                              void* d_out, int out_size, void* d_ws, size_t ws_size,
                              hipStream_t stream) {
    const float* xyz   = (const float*)d_in[0];
    const float* fts   = (const float*)d_in[1];
    const int*   valid = (const int*)d_in[2];

    float* out     = (float*)d_out;
    float* all_fts = out;                                  // (2,256,768)
    float* mask    = out + (size_t)BATCH * NGRP * FDIM;    // (2,256)
    float* centers = mask + (size_t)BATCH * NGRP;          // (2,256,3)

    const size_t mb16 = (size_t)MB_ROUNDS * FPS_NBLK * 16 * 8;   // 2,088,960
    unsigned long long* mb = (unsigned long long*)d_ws;
    unsigned int* dcnt = (unsigned int*)((char*)d_ws + mb16);    // 8 replicas x 64B

    // mailbox + counters must be zero at the start of EVERY call
    if (ws_size >= mb16 + DC_REP * 64) {
        hipMemsetAsync(d_ws, 0, mb16 + DC_REP * 64, stream);
        fused_kernel<16><<<dim3(GRID_BLK), dim3(256), 0, stream>>>(
            xyz, fts, valid, all_fts, mask, centers, mb, dcnt);
    } else {
        hipMemsetAsync(d_ws, 0, 131072, stream);
        fps_kernel<<<dim3(FPS_NBLK), dim3(FPS_TPB), 0, stream>>>(xyz, centers, mb);
        knn_agg_kernel<<<dim3(BATCH * NGRP), dim3(256), 0, stream>>>(
            xyz, fts, valid, centers, all_fts, mask);
    }
}

// Round 21
// 587.803 us; speedup vs baseline: 1.0112x; 1.0112x over previous
//
#include <hip/hip_runtime.h>
#include <cstddef>

#define NPTS   40000
#define NGRP   256
#define GSZ    64
#define FDIM   768
#define BATCH  2

#define FPS_BPB    32
#define FPS_NBLK   (FPS_BPB * BATCH)   // 64
#define FPS_TPB    64
#define FPS_PPB    (NPTS / FPS_BPB)    // 1250
#define FPS_PPT    20
#define MB_ROUNDS  255
#define NCHUNK     (NPTS / 64)         // 625

#define W_NBLK     (BATCH * NGRP)      // 512 worker blocks
#define GRID_BLK   (FPS_NBLK + W_NBLK) // 576

__device__ __forceinline__ unsigned long long mk32(float v, unsigned tb) {
    return ((unsigned long long)__float_as_uint(v) << 16) | (unsigned long long)tb;
}
__device__ __forceinline__ float d2f(float px, float py, float pz,
                                     float cx, float cy, float cz) {
    float dx = __fsub_rn(px, cx), dy = __fsub_rn(py, cy), dz = __fsub_rn(pz, cz);
    return __fmaf_rn(dz, dz, __fmaf_rn(dy, dy, __fmul_rn(dx, dx)));
}
__device__ __forceinline__ unsigned long long knn_key(double v, int idx) {
    unsigned long long bits = (unsigned long long)__double_as_longlong(v);
    return (bits & 0xFFFFFFFFFFFF0000ull) | (unsigned long long)(unsigned)idx;
}
__device__ __forceinline__ unsigned long long fps_mk64(double v, unsigned tb) {
    return (((unsigned long long)__double_as_longlong(v)) & 0xFFFFFFFFFFFF0000ull)
         | (unsigned long long)tb;
}
__device__ __forceinline__ unsigned long long wave_max_u64(unsigned long long k) {
#pragma unroll
    for (int off = 32; off >= 1; off >>= 1) {
        unsigned long long o = __shfl_xor(k, off, 64);
        k = o > k ? o : k;
    }
    return k;
}

#define LANE_RESCAN(OUT)                                                    \
    {                                                                       \
        unsigned long long bb_ = 0ull;                                      \
        _Pragma("unroll")                                                   \
        for (int j_ = 0; j_ < FPS_PPT; ++j_) {                              \
            bool live_ = (((vmask >> j_) & 1u) != 0u) &&                    \
                         (((cons >> j_) & 1u) == 0u);                       \
            unsigned long long kk_ = live_                                  \
                ? mk32(dist[j_], tb0 - (unsigned)(j_ << 6)) : 0ull;         \
            bb_ = kk_ > bb_ ? kk_ : bb_;                                    \
        }                                                                   \
        OUT = bb_;                                                          \
    }

// ============ fused: FPS (blocks 0..63, 1 wave) + workers (one per center) ============
template<int M>
__global__ void __launch_bounds__(256) fused_kernel(
    const float* __restrict__ xyz,
    const float* __restrict__ fts,
    const int*   __restrict__ valid,
    float* __restrict__ all_fts,
    float* __restrict__ mask,
    float* __restrict__ centers,
    unsigned long long* __restrict__ mb,      // [MB_ROUNDS][64*M], pre-zeroed
    unsigned int* __restrict__ dcnt)          // [BATCH] done counters, pre-zeroed
{
    constexpr int Q     = (FPS_BPB * M) / 64;
    constexpr int MB_RW = FPS_NBLK * M;

    const int bid = blockIdx.x;
    const int tid = threadIdx.x;

    if (bid < FPS_NBLK) {
        // ================= FPS role: R13/R16-proven fps_spec<16> f32 =========
        if (tid >= 64) return;               // waves 1..3 exit
        const int lane = tid;
        const int b    = bid >> 5;
        const int lb   = bid & 31;
        const float* __restrict__ X = xyz + (size_t)b * NPTS * 3;
        const int base = lb * FPS_PPB;
        const unsigned tb0 = 0xFFFFu - (unsigned)(base + lane);

        float px[FPS_PPT], py[FPS_PPT], pz[FPS_PPT], dist[FPS_PPT];
        unsigned vmask = 0;
#pragma unroll
        for (int j = 0; j < FPS_PPT; ++j) {
            int loc = lane + j * FPS_TPB;
            bool ok = loc < FPS_PPB;
            int i   = base + (ok ? loc : 0);
            px[j] = X[i * 3 + 0]; py[j] = X[i * 3 + 1]; pz[j] = X[i * 3 + 2];
            if (ok) vmask |= 1u << j;
        }
        {
            float cx = X[0], cy = X[1], cz = X[2];
            if (lb == 0 && lane == 0) {
                centers[(size_t)(b * NGRP) * 3 + 0] = cx;
                centers[(size_t)(b * NGRP) * 3 + 1] = cy;
                centers[(size_t)(b * NGRP) * 3 + 2] = cz;
                __hip_atomic_store(&dcnt[b], 1u,
                                   __ATOMIC_RELEASE, __HIP_MEMORY_SCOPE_AGENT);
            }
#pragma unroll
            for (int j = 0; j < FPS_PPT; ++j)
                dist[j] = d2f(px[j], py[j], pz[j], cx, cy, cz);
        }

        int done = 1;
        int r = 0;

        while (done < NGRP) {
            unsigned long long s0 = 0, s1 = 0, s2 = 0, s3 = 0;
#pragma unroll
            for (int j = 0; j < FPS_PPT; ++j) {
                bool live = ((vmask >> j) & 1u) != 0u;
                unsigned long long kk = live ? mk32(dist[j], tb0 - (unsigned)(j << 6)) : 0ull;
                unsigned long long t;
                t = kk > s0 ? kk : s0;  kk = kk > s0 ? s0 : kk;  s0 = t;
                t = kk > s1 ? kk : s1;  kk = kk > s1 ? s1 : kk;  s1 = t;
                t = kk > s2 ? kk : s2;  kk = kk > s2 ? s2 : kk;  s2 = t;
                s3 = kk > s3 ? kk : s3;
            }
            unsigned cons = 0;

            unsigned long long myMsg = 0;
#pragma unroll
            for (int i = 0; i < M; ++i) {
                if (s0 == 0ull) LANE_RESCAN(s0);
                unsigned long long g = wave_max_u64(s0);
                if (s0 == g && g != 0ull) {
                    unsigned idx = 0xFFFFu - (unsigned)(g & 0xFFFFull);
                    unsigned jj  = (idx - (unsigned)(base + lane)) >> 6;
                    cons |= 1u << jj;
                    s0 = s1; s1 = s2; s2 = s3; s3 = 0ull;
                }
                myMsg = (lane == i) ? g : myMsg;
            }

            if (lane < M)
                __hip_atomic_store(&mb[(size_t)r * MB_RW + bid * M + lane], myMsg,
                                   __ATOMIC_RELAXED, __HIP_MEMORY_SCOPE_AGENT);

            const unsigned long long* pb = mb + (size_t)r * MB_RW + b * (FPS_BPB * M);
            unsigned long long w[Q];
#pragma unroll
            for (int q = 0; q < Q; ++q)
                w[q] = __hip_atomic_load(pb + lane + 64 * q,
                                         __ATOMIC_RELAXED, __HIP_MEMORY_SCOPE_AGENT);
            for (;;) {
                bool miss = false;
#pragma unroll
                for (int q = 0; q < Q; ++q) miss |= (w[q] == 0ull);
                if (__ballot(miss) == 0ull) break;
#pragma unroll
                for (int q = 0; q < Q; ++q)
                    if (w[q] == 0ull)
                        w[q] = __hip_atomic_load(pb + lane + 64 * q,
                                                 __ATOMIC_RELAXED, __HIP_MEMORY_SCOPE_AGENT);
            }

            unsigned long long tl = 0;
            if ((lane & (M - 1)) == (M - 1)) {
#pragma unroll
                for (int q = 0; q < Q; ++q) tl = w[q] > tl ? w[q] : tl;
            }
            const unsigned long long T = wave_max_u64(tl);

            float cvv[Q]; unsigned ctb[Q]; unsigned long long ck[Q];
            float ccx[Q], ccy[Q], ccz[Q];
#pragma unroll
            for (int q = 0; q < Q; ++q) {
                ck[q]  = w[q];
                ctb[q] = (unsigned)(w[q] & 0xFFFFull);
                cvv[q] = __uint_as_float((unsigned)(w[q] >> 16));
                int ii = (int)(0xFFFFu - ctb[q]);
                ccx[q] = X[ii * 3 + 0]; ccy[q] = X[ii * 3 + 1]; ccz[q] = X[ii * 3 + 2];
            }
            unsigned consq = 0;

#pragma unroll 1
            for (int s = 0; s < 64; ++s) {
                unsigned long long lk = 0;
#pragma unroll
                for (int q = 0; q < Q; ++q) {
                    unsigned long long kk = ((consq >> q) & 1u) ? 0ull : ck[q];
                    lk = kk > lk ? kk : lk;
                }
                unsigned long long g = wave_max_u64(lk);
                if (s > 0 && g < T) break;

                float sx = ccx[0], sy = ccy[0], sz = ccz[0];
#pragma unroll
                for (int q = 0; q < Q; ++q) {
                    bool hit = (ck[q] == g) && !((consq >> q) & 1u);
                    consq |= hit ? (1u << q) : 0u;
                    sx = hit ? ccx[q] : sx;
                    sy = hit ? ccy[q] : sy;
                    sz = hit ? ccz[q] : sz;
                }
                unsigned long long om = __ballot(lk == g);
                int owner = __ffsll((long long)om) - 1;
                float wx = __shfl(sx, owner, 64);
                float wy = __shfl(sy, owner, 64);
                float wz = __shfl(sz, owner, 64);
                if (lb == 0 && lane == 0) {
                    centers[((size_t)b * NGRP + done) * 3 + 0] = wx;
                    centers[((size_t)b * NGRP + done) * 3 + 1] = wy;
                    centers[((size_t)b * NGRP + done) * 3 + 2] = wz;
                }
#pragma unroll
                for (int q = 0; q < Q; ++q) {
                    cvv[q] = fminf(cvv[q], d2f(ccx[q], ccy[q], ccz[q], wx, wy, wz));
                    ck[q]  = ((consq >> q) & 1u) ? 0ull
                           : (((unsigned long long)__float_as_uint(cvv[q]) << 16)
                              | (unsigned long long)ctb[q]);
                }
#pragma unroll
                for (int j = 0; j < FPS_PPT; ++j)
                    dist[j] = fminf(dist[j], d2f(px[j], py[j], pz[j], wx, wy, wz));
                ++done;
                if (done == NGRP) break;
            }
            // publish progress once per round (release covers all center writes)
            if (lb == 0 && lane == 0)
                __hip_atomic_store(&dcnt[b], (unsigned)done,
                                   __ATOMIC_RELEASE, __HIP_MEMORY_SCOPE_AGENT);
            ++r;
        }
        return;
    }

    // ================= Worker role: one block per center (R12-proven body) ====
    const int w   = bid - FPS_NBLK;            // [0, 512)
    const int c   = (w >> 1) + ((w & 1) << 8); // interleave batches
    const int b   = c >> 8;
    const int wid  = tid >> 6;
    const int lane = tid & 63;
    const float* __restrict__ X = xyz + (size_t)b * NPTS * 3;

    // wait until this center is published
    {
        const unsigned int want = (unsigned)(c & (NGRP - 1)) + 1u;
        while (__hip_atomic_load(&dcnt[b], __ATOMIC_RELAXED, __HIP_MEMORY_SCOPE_AGENT) < want)
            __builtin_amdgcn_s_sleep(64);
        __builtin_amdgcn_fence(__ATOMIC_ACQUIRE, "agent");
    }

    const double cx = (double)centers[(size_t)c * 3 + 0];
    const double cy = (double)centers[(size_t)c * 3 + 1];
    const double cz = (double)centers[(size_t)c * 3 + 2];

    unsigned long long slot;
    {
        int i = wid * 64 + lane;
        float x = X[i * 3 + 0], y = X[i * 3 + 1], z = X[i * 3 + 2];
        double dx = (double)x - cx, dy = (double)y - cy, dz = (double)z - cz;
        slot = knn_key(dx * dx + dy * dy + dz * dz, i);
    }
    unsigned long long tau = wave_max_u64(slot);

    float ax, ay, az, bx, by, bz;
    {
        int ia = (wid + 4) * 64 + lane;
        ax = X[ia * 3 + 0]; ay = X[ia * 3 + 1]; az = X[ia * 3 + 2];
        int sb = wid + 8 < NCHUNK ? wid + 8 : NCHUNK - 1;
        int ib = sb * 64 + lane;
        bx = X[ib * 3 + 0]; by = X[ib * 3 + 1]; bz = X[ib * 3 + 2];
    }
    for (int s = wid + 4; s < NCHUNK; s += 4) {
        float x = ax, y = ay, z = az;
        ax = bx; ay = by; az = bz;
        int sp = s + 8 < NCHUNK ? s + 8 : NCHUNK - 1;
        int ip = sp * 64 + lane;
        bx = X[ip * 3 + 0]; by = X[ip * 3 + 1]; bz = X[ip * 3 + 2];

        int i = s * 64 + lane;
        double dx = (double)x - cx, dy = (double)y - cy, dz = (double)z - cz;
        unsigned long long key = knn_key(dx * dx + dy * dy + dz * dz, i);

        unsigned long long cand = __ballot(key < tau);
        while (cand) {
            int l = __ffsll(cand) - 1;
            cand &= cand - 1;
            unsigned long long kc = __shfl(key, l, 64);
            if (kc < tau) {
                unsigned long long om = __ballot(slot == tau);
                int owner = __ffsll(om) - 1;
                if (lane == owner) slot = kc;
                tau = wave_max_u64(slot);
            }
        }
    }

    __shared__ unsigned long long skey[256];
    __shared__ int s_nbr[GSZ];
    skey[tid] = slot;
    __syncthreads();
#pragma unroll
    for (int k = 2; k <= 256; k <<= 1) {
        for (int j = k >> 1; j > 0; j >>= 1) {
            int ixj = tid ^ j;
            if (ixj > tid) {
                unsigned long long a = skey[tid], bb = skey[ixj];
                bool up = ((tid & k) == 0);
                if ((a > bb) == up) { skey[tid] = bb; skey[ixj] = a; }
            }
            __syncthreads();
        }
    }

    if (wid == 0) {
        int idx = (int)(skey[lane] & 0xFFFFull);
        s_nbr[lane] = idx;
        int v = valid[b * NPTS + idx];
        unsigned long long vb = __ballot(v != 0);
        if (lane == 0) mask[c] = vb ? 1.0f : 0.0f;
    }
    __syncthreads();

    const float* __restrict__ F = fts + (size_t)b * NPTS * FDIM;
    float a0 = 0.f, a1 = 0.f, a2 = 0.f, b0 = 0.f, b1 = 0.f, b2 = 0.f;
#pragma unroll 1
    for (int j = 0; j < GSZ; j += 2) {
        const float* r0 = F + (size_t)s_nbr[j]     * FDIM;
        const float* r1 = F + (size_t)s_nbr[j + 1] * FDIM;
        a0 += r0[tid];       b0 += r1[tid];
        a1 += r0[tid + 256]; b1 += r1[tid + 256];
        a2 += r0[tid + 512]; b2 += r1[tid + 512];
    }
    float* o = all_fts + (size_t)c * FDIM;
    o[tid]       = (a0 + b0) * 0.015625f;
    o[tid + 256] = (a1 + b1) * 0.015625f;
    o[tid + 512] = (a2 + b2) * 0.015625f;
}

// ---------------- R4-proven fallback FPS (f64, 1 key/block/iter) ----------------
__global__ void __launch_bounds__(FPS_TPB) fps_kernel(
    const float* __restrict__ xyz,
    float* __restrict__ centers,
    unsigned long long* __restrict__ keys)
{
    const int bid  = blockIdx.x;
    const int b    = bid >> 5;
    const int lb   = bid & 31;
    const int lane = threadIdx.x;
    const float* __restrict__ X = xyz + (size_t)b * NPTS * 3;
    const int base  = lb * FPS_PPB;
    const int gbase = base + lane;

    double px[FPS_PPT], py[FPS_PPT], pz[FPS_PPT], dist[FPS_PPT];
#pragma unroll
    for (int j = 0; j < FPS_PPT; ++j) {
        int loc = lane + j * FPS_TPB;
        bool ok = loc < FPS_PPB;
        int i   = base + (ok ? loc : 0);
        px[j] = (double)X[i * 3 + 0];
        py[j] = (double)X[i * 3 + 1];
        pz[j] = (double)X[i * 3 + 2];
        dist[j] = ok ? 1e18 : -1.0;
    }
    double cx = (double)X[0], cy = (double)X[1], cz = (double)X[2];
    if (lb == 0 && lane == 0) {
        centers[(size_t)(b * NGRP) * 3 + 0] = X[0];
        centers[(size_t)(b * NGRP) * 3 + 1] = X[1];
        centers[(size_t)(b * NGRP) * 3 + 2] = X[2];
    }
    for (int it = 0; it < NGRP - 1; ++it) {
        double bd = -2.0; int bj = 0;
#pragma unroll
        for (int j = 0; j < FPS_PPT; ++j) {
            double dx = px[j] - cx, dy = py[j] - cy, dz = pz[j] - cz;
            double d  = fma(dz, dz, fma(dy, dy, dx * dx));
            double nd = dist[j] < d ? dist[j] : d;
            dist[j] = nd;
            bool better = nd > bd;
            bd = better ? nd : bd;
            bj = better ? j  : bj;
        }
        unsigned long long key = fps_mk64(bd, 0xFFFFu - (unsigned)(gbase + (bj << 6)));
        key = wave_max_u64(key);
        if (lane == 0)
            __hip_atomic_store(&keys[it * FPS_NBLK + bid], key,
                               __ATOMIC_RELAXED, __HIP_MEMORY_SCOPE_AGENT);
        unsigned long long pk = 0;
        if (lane < FPS_BPB) {
            const unsigned long long* sp = &keys[it * FPS_NBLK + b * FPS_BPB + lane];
            do {
                pk = __hip_atomic_load(sp, __ATOMIC_RELAXED, __HIP_MEMORY_SCOPE_AGENT);
            } while (pk == 0ull);
        }
        unsigned long long g = wave_max_u64(pk);
        int widx = 0xFFFF - (int)(g & 0xFFFFull);
        float wx = X[widx * 3 + 0], wy = X[widx * 3 + 1], wz = X[widx * 3 + 2];
        cx = (double)wx; cy = (double)wy; cz = (double)wz;
        if (lb == 0 && lane == 0) {
            centers[(size_t)(b * NGRP + it + 1) * 3 + 0] = wx;
            centers[(size_t)(b * NGRP + it + 1) * 3 + 1] = wy;
            centers[(size_t)(b * NGRP + it + 1) * 3 + 2] = wz;
        }
    }
}

// -------- R12-proven fused KNN (f64) + agg + mask (fallback path) --------
__global__ void __launch_bounds__(256) knn_agg_kernel(
    const float* __restrict__ xyz,
    const float* __restrict__ fts,
    const int*   __restrict__ valid,
    const float* __restrict__ centers,
    float* __restrict__ all_fts,
    float* __restrict__ mask)
{
    const int c    = blockIdx.x;
    const int b    = c >> 8;
    const int tid  = threadIdx.x;
    const int wid  = tid >> 6;
    const int lane = tid & 63;
    const float* __restrict__ X = xyz + (size_t)b * NPTS * 3;

    const double cx = (double)centers[(size_t)c * 3 + 0];
    const double cy = (double)centers[(size_t)c * 3 + 1];
    const double cz = (double)centers[(size_t)c * 3 + 2];

    unsigned long long slot;
    {
        int i = wid * 64 + lane;
        float x = X[i * 3 + 0], y = X[i * 3 + 1], z = X[i * 3 + 2];
        double dx = (double)x - cx, dy = (double)y - cy, dz = (double)z - cz;
        slot = knn_key(dx * dx + dy * dy + dz * dz, i);
    }
    unsigned long long tau = wave_max_u64(slot);

    float ax, ay, az, bx, by, bz;
    {
        int ia = (wid + 4) * 64 + lane;
        ax = X[ia * 3 + 0]; ay = X[ia * 3 + 1]; az = X[ia * 3 + 2];
        int sb = wid + 8 < NCHUNK ? wid + 8 : NCHUNK - 1;
        int ib = sb * 64 + lane;
        bx = X[ib * 3 + 0]; by = X[ib * 3 + 1]; bz = X[ib * 3 + 2];
    }
    for (int s = wid + 4; s < NCHUNK; s += 4) {
        float x = ax, y = ay, z = az;
        ax = bx; ay = by; az = bz;
        int sp = s + 8 < NCHUNK ? s + 8 : NCHUNK - 1;
        int ip = sp * 64 + lane;
        bx = X[ip * 3 + 0]; by = X[ip * 3 + 1]; bz = X[ip * 3 + 2];

        int i = s * 64 + lane;
        double dx = (double)x - cx, dy = (double)y - cy, dz = (double)z - cz;
        unsigned long long key = knn_key(dx * dx + dy * dy + dz * dz, i);

        unsigned long long cand = __ballot(key < tau);
        while (cand) {
            int l = __ffsll(cand) - 1;
            cand &= cand - 1;
            unsigned long long kc = __shfl(key, l, 64);
            if (kc < tau) {
                unsigned long long om = __ballot(slot == tau);
                int owner = __ffsll(om) - 1;
                if (lane == owner) slot = kc;
                tau = wave_max_u64(slot);
            }
        }
    }

    __shared__ unsigned long long skey[256];
    __shared__ int s_nbr[GSZ];
    skey[tid] = slot;
    __syncthreads();
#pragma unroll
    for (int k = 2; k <= 256; k <<= 1) {
        for (int j = k >> 1; j > 0; j >>= 1) {
            int ixj = tid ^ j;
            if (ixj > tid) {
                unsigned long long a = skey[tid], bb = skey[ixj];
                bool up = ((tid & k) == 0);
                if ((a > bb) == up) { skey[tid] = bb; skey[ixj] = a; }
            }
            __syncthreads();
        }
    }

    if (wid == 0) {
        int idx = (int)(skey[lane] & 0xFFFFull);
        s_nbr[lane] = idx;
        int v = valid[b * NPTS + idx];
        unsigned long long vb = __ballot(v != 0);
        if (lane == 0) mask[c] = vb ? 1.0f : 0.0f;
    }
    __syncthreads();

    const float* __restrict__ F = fts + (size_t)b * NPTS * FDIM;
    float a0 = 0.f, a1 = 0.f, a2 = 0.f, b0 = 0.f, b1 = 0.f, b2 = 0.f;
#pragma unroll 1
    for (int j = 0; j < GSZ; j += 2) {
        const float* r0 = F + (size_t)s_nbr[j]     * FDIM;
        const float* r1 = F + (size_t)s_nbr[j + 1] * FDIM;
        a0 += r0[tid];       b0 += r1[tid];
        a1 += r0[tid + 256]; b1 += r1[tid + 256];
        a2 += r0[tid + 512]; b2 += r1[tid + 512];
    }
    float* o = all_fts + (size_t)c * FDIM;
    o[tid]       = (a0 + b0) * 0.015625f;
    o[tid + 256] = (a1 + b1) * 0.015625f;
    o[tid + 512] = (a2 + b2) * 0.015625f;
}

extern "C" void kernel_launch(void* const* d_in, const int* in_sizes, int n_in,
                              void* d_out, int out_size, void* d_ws, size_t ws_size,
                              hipStream_t stream) {
    const float* xyz   = (const float*)d_in[0];
    const float* fts   = (const float*)d_in[1];
    const int*   valid = (const int*)d_in[2];

    float* out     = (float*)d_out;
    float* all_fts = out;                                  // (2,256,768)
    float* mask    = out + (size_t)BATCH * NGRP * FDIM;    // (2,256)
    float* centers = mask + (size_t)BATCH * NGRP;          // (2,256,3)

    const size_t mb16 = (size_t)MB_ROUNDS * FPS_NBLK * 16 * 8;   // 2,088,960
    unsigned long long* mb = (unsigned long long*)d_ws;
    unsigned int* dcnt = (unsigned int*)((char*)d_ws + mb16);    // 2 u32

    // mailbox + counters must be zero at the start of EVERY call
    if (ws_size >= mb16 + 64) {
        hipMemsetAsync(d_ws, 0, mb16 + 64, stream);
        fused_kernel<16><<<dim3(GRID_BLK), dim3(256), 0, stream>>>(
            xyz, fts, valid, all_fts, mask, centers, mb, dcnt);
    } else {
        hipMemsetAsync(d_ws, 0, 131072, stream);
        fps_kernel<<<dim3(FPS_NBLK), dim3(FPS_TPB), 0, stream>>>(xyz, centers, mb);
        knn_agg_kernel<<<dim3(BATCH * NGRP), dim3(256), 0, stream>>>(
            xyz, fts, valid, centers, all_fts, mask);
    }
}